// Round 3
// baseline (111.919 us; speedup 1.0000x reference)
//
#include <hip/hip_runtime.h>
#include <math.h>

#define N_PTS   4000000
#define NQUADS  (N_PTS / 4)        // 1,000,000 quads; 1 quad = 4 pts = 3 float4
#define NTHREADS 256
#define NBLOCKS  2048

// ---------------------------------------------------------------------------
// Single fused kernel:
//   - thread 0 computes R,T from pose scalars -> LDS
//   - grid-stride loop, 4 points (3 contiguous float4) per thread-iteration
//   - per-block deterministic reduction -> partials[block]
//   - "last block" (modulo epoch counter, initial-value-agnostic) sums the
//     2048 partials in fixed order and writes loss. No resets needed between
//     graph replays: each call performs exactly NBLOCKS increments, so exactly
//     one block sees (old % NBLOCKS) == NBLOCKS-1 regardless of start value.
// ---------------------------------------------------------------------------
__global__ __launch_bounds__(NTHREADS) void proj_kernel(
    const float4* __restrict__ pts,
    const float* __restrict__ xp, const float* __restrict__ yp,
    const float* __restrict__ zp, const float* __restrict__ rollp,
    const float* __restrict__ pitchp, const float* __restrict__ yawp,
    float4* __restrict__ vout, float* __restrict__ partials,
    unsigned int* __restrict__ counter, float* __restrict__ loss_out)
{
    __shared__ float sRT[12];
    __shared__ float sred[NTHREADS / 64];
    __shared__ int   sIsLast;

    if (threadIdx.x == 0) {
        const float r = rollp[0], p = pitchp[0], ya = yawp[0];
        const float cr = cosf(r),  sr = sinf(r);
        const float cp = cosf(p),  sp = sinf(p);
        const float cy = cosf(ya), sy = sinf(ya);
        // R = Rx @ Ry @ Rz, row-major
        sRT[0] = cp * cy;                 sRT[1] = -cp * sy;                sRT[2] = sp;
        sRT[3] = cr * sy + sr * sp * cy;  sRT[4] = cr * cy - sr * sp * sy;  sRT[5] = -sr * cp;
        sRT[6] = sr * sy - cr * sp * cy;  sRT[7] = sr * cy + cr * sp * sy;  sRT[8] = cr * cp;
        sRT[9] = xp[0]; sRT[10] = yp[0]; sRT[11] = zp[0];
    }
    __syncthreads();

    const float R00 = sRT[0], R01 = sRT[1], R02 = sRT[2];
    const float R10 = sRT[3], R11 = sRT[4], R12 = sRT[5];
    const float R20 = sRT[6], R21 = sRT[7], R22 = sRT[8];
    const float Tx  = sRT[9], Ty  = sRT[10], Tz = sRT[11];

    float acc = 0.0f;
    const int tid    = blockIdx.x * NTHREADS + threadIdx.x;
    const int stride = NBLOCKS * NTHREADS;

    for (int q = tid; q < NQUADS; q += stride) {
        const float4 a = pts[3 * q + 0];
        const float4 b = pts[3 * q + 1];
        const float4 c = pts[3 * q + 2];

        const float px[4] = {a.x, a.w, b.z, c.y};
        const float py[4] = {a.y, b.x, b.w, c.z};
        const float pz[4] = {a.z, b.y, c.x, c.w};
        float vx[4], vy[4], vz[4];

#pragma unroll
        for (int k = 0; k < 4; ++k) {
            const float q0 = px[k] - Tx;
            const float q1 = py[k] - Ty;
            const float q2 = pz[k] - Tz;
            // v = q @ R   (v_j = sum_i q_i * R[i][j])
            const float v0 = q0 * R00 + q1 * R10 + q2 * R20;
            const float v1 = q0 * R01 + q1 * R11 + q2 * R21;
            const float v2 = q0 * R02 + q1 * R12 + q2 * R22;

            const bool dist = (v2 > 1.0f) && (v2 < 10.0f);

            // ph = v @ K^T ; ph[2] == v2
            const float ph0 = v0 * 600.0f + v2 * 640.0f;
            const float ph1 = v1 * 600.0f + v2 * 360.0f;
            const float u = ph0 / v2;            // IEEE div: mask-exactness
            const float w = ph1 / v2;
            const bool fov = (v2 > 0.0f) && (u > 1.0f) && (u < 1279.0f) &&
                             (w > 1.0f) && (w < 719.0f);
            const bool m = dist && fov;

            const float d = sqrtf(v0 * v0 + v1 * v1 + v2 * v2);
            const float t = (d - 4.0f) * 0.5f;   // (d - MU) / SIGMA
            acc += m ? __expf(-0.5f * t * t) : 0.0f;

            vx[k] = m ? v0 : 0.0f;
            vy[k] = m ? v1 : 0.0f;
            vz[k] = m ? v2 : 0.0f;
        }

        vout[3 * q + 0] = make_float4(vx[0], vy[0], vz[0], vx[1]);
        vout[3 * q + 1] = make_float4(vy[1], vz[1], vx[2], vy[2]);
        vout[3 * q + 2] = make_float4(vz[2], vx[3], vy[3], vz[3]);
    }

    // --- per-block deterministic reduction ---
#pragma unroll
    for (int off = 32; off > 0; off >>= 1)
        acc += __shfl_down(acc, off, 64);
    if ((threadIdx.x & 63) == 0) sred[threadIdx.x >> 6] = acc;
    __syncthreads();
    if (threadIdx.x == 0) {
        float tot = 0.0f;
#pragma unroll
        for (int i = 0; i < NTHREADS / 64; ++i) tot += sred[i];
        partials[blockIdx.x] = tot;
        __threadfence();                                 // partial visible
        const unsigned int old = atomicAdd(counter, 1u); // device-scope
        sIsLast = ((old % NBLOCKS) == NBLOCKS - 1) ? 1 : 0;
    }
    __syncthreads();

    // --- last arriving block folds partials -> loss ---
    if (sIsLast) {
        __threadfence();                                 // acquire partials
        float a2 = 0.0f;
        for (int i = threadIdx.x; i < NBLOCKS; i += NTHREADS)
            a2 += partials[i];
#pragma unroll
        for (int off = 32; off > 0; off >>= 1)
            a2 += __shfl_down(a2, off, 64);
        if ((threadIdx.x & 63) == 0) sred[threadIdx.x >> 6] = a2;
        __syncthreads();
        if (threadIdx.x == 0) {
            float tot = 0.0f;
#pragma unroll
            for (int i = 0; i < NTHREADS / 64; ++i) tot += sred[i];
            loss_out[0] = 1.0f / (tot + 1e-6f);
        }
    }
}

extern "C" void kernel_launch(void* const* d_in, const int* in_sizes, int n_in,
                              void* d_out, int out_size, void* d_ws, size_t ws_size,
                              hipStream_t stream) {
    const float4* pts  = (const float4*)d_in[0];
    const float* x     = (const float*)d_in[1];
    const float* y     = (const float*)d_in[2];
    const float* z     = (const float*)d_in[3];
    const float* roll  = (const float*)d_in[4];
    const float* pitch = (const float*)d_in[5];
    const float* yaw   = (const float*)d_in[6];

    float* out            = (float*)d_out;                 // [0..12M) verts, [12M] loss
    float* parts          = (float*)d_ws;                  // NBLOCKS floats
    unsigned int* counter = (unsigned int*)((float*)d_ws + NBLOCKS);

    proj_kernel<<<NBLOCKS, NTHREADS, 0, stream>>>(
        pts, x, y, z, roll, pitch, yaw,
        (float4*)out, parts, counter, out + (size_t)3 * N_PTS);
}

// Round 4
// 30.743 us; speedup vs baseline: 3.6405x; 3.6405x over previous
//
#include <hip/hip_runtime.h>
#include <math.h>

#define N_PTS   4000000
#define NQUADS  (N_PTS / 4)        // 1,000,000 quads; 1 quad = 4 pts = 3 float4
#define NTHREADS 256
#define NBLOCKS  ((NQUADS + NTHREADS - 1) / NTHREADS)   // 3907

// ---------------------------------------------------------------------------
// Main kernel: pose fused (thread 0 -> LDS -> barrier), 1 quad per thread,
// per-block deterministic reduction -> partials[block]. NO device-scope
// fences (round-3 lesson: __threadfence => L2 writeback/invalidate storm).
// ---------------------------------------------------------------------------
__global__ __launch_bounds__(NTHREADS) void proj_kernel(
    const float4* __restrict__ pts,
    const float* __restrict__ xp, const float* __restrict__ yp,
    const float* __restrict__ zp, const float* __restrict__ rollp,
    const float* __restrict__ pitchp, const float* __restrict__ yawp,
    float4* __restrict__ vout, float* __restrict__ partials)
{
    __shared__ float sRT[12];
    __shared__ float sred[NTHREADS / 64];

    if (threadIdx.x == 0) {
        const float r = rollp[0], p = pitchp[0], ya = yawp[0];
        const float cr = cosf(r),  sr = sinf(r);
        const float cp = cosf(p),  sp = sinf(p);
        const float cy = cosf(ya), sy = sinf(ya);
        // R = Rx @ Ry @ Rz, row-major
        sRT[0] = cp * cy;                 sRT[1] = -cp * sy;                sRT[2] = sp;
        sRT[3] = cr * sy + sr * sp * cy;  sRT[4] = cr * cy - sr * sp * sy;  sRT[5] = -sr * cp;
        sRT[6] = sr * sy - cr * sp * cy;  sRT[7] = sr * cy + cr * sp * sy;  sRT[8] = cr * cp;
        sRT[9] = xp[0]; sRT[10] = yp[0]; sRT[11] = zp[0];
    }
    __syncthreads();

    const float R00 = sRT[0], R01 = sRT[1], R02 = sRT[2];
    const float R10 = sRT[3], R11 = sRT[4], R12 = sRT[5];
    const float R20 = sRT[6], R21 = sRT[7], R22 = sRT[8];
    const float Tx  = sRT[9], Ty  = sRT[10], Tz = sRT[11];

    const int q = blockIdx.x * NTHREADS + threadIdx.x;
    float acc = 0.0f;

    if (q < NQUADS) {
        const float4 a = pts[3 * q + 0];
        const float4 b = pts[3 * q + 1];
        const float4 c = pts[3 * q + 2];

        const float px[4] = {a.x, a.w, b.z, c.y};
        const float py[4] = {a.y, b.x, b.w, c.z};
        const float pz[4] = {a.z, b.y, c.x, c.w};
        float vx[4], vy[4], vz[4];

#pragma unroll
        for (int k = 0; k < 4; ++k) {
            const float q0 = px[k] - Tx;
            const float q1 = py[k] - Ty;
            const float q2 = pz[k] - Tz;
            // v = q @ R   (v_j = sum_i q_i * R[i][j])
            const float v0 = q0 * R00 + q1 * R10 + q2 * R20;
            const float v1 = q0 * R01 + q1 * R11 + q2 * R21;
            const float v2 = q0 * R02 + q1 * R12 + q2 * R22;

            const bool dist = (v2 > 1.0f) && (v2 < 10.0f);

            // ph = v @ K^T ; ph[2] == v2
            const float ph0 = v0 * 600.0f + v2 * 640.0f;
            const float ph1 = v1 * 600.0f + v2 * 360.0f;
            const float u = ph0 / v2;            // IEEE div: mask-exactness
            const float w = ph1 / v2;
            const bool fov = (v2 > 0.0f) && (u > 1.0f) && (u < 1279.0f) &&
                             (w > 1.0f) && (w < 719.0f);
            const bool m = dist && fov;

            const float d = sqrtf(v0 * v0 + v1 * v1 + v2 * v2);
            const float t = (d - 4.0f) * 0.5f;   // (d - MU) / SIGMA
            acc += m ? __expf(-0.5f * t * t) : 0.0f;

            vx[k] = m ? v0 : 0.0f;
            vy[k] = m ? v1 : 0.0f;
            vz[k] = m ? v2 : 0.0f;
        }

        vout[3 * q + 0] = make_float4(vx[0], vy[0], vz[0], vx[1]);
        vout[3 * q + 1] = make_float4(vy[1], vz[1], vx[2], vy[2]);
        vout[3 * q + 2] = make_float4(vz[2], vx[3], vy[3], vz[3]);
    }

    // Per-block deterministic reduction (all threads participate; acc=0 for
    // out-of-range threads).
#pragma unroll
    for (int off = 32; off > 0; off >>= 1)
        acc += __shfl_down(acc, off, 64);
    if ((threadIdx.x & 63) == 0) sred[threadIdx.x >> 6] = acc;
    __syncthreads();
    if (threadIdx.x == 0) {
        float tot = 0.0f;
#pragma unroll
        for (int i = 0; i < NTHREADS / 64; ++i) tot += sred[i];
        partials[blockIdx.x] = tot;
    }
}

// ---------------------------------------------------------------------------
// Loss kernel: sum partials in fixed order -> loss. Separate dispatch =
// the cheap cross-block synchronization point (no fences needed).
// ---------------------------------------------------------------------------
__global__ __launch_bounds__(256) void loss_kernel(const float* __restrict__ partials,
                                                   int n, float* __restrict__ loss_out) {
    __shared__ float sdata[4];
    float acc = 0.0f;
    for (int i = threadIdx.x; i < n; i += 256) acc += partials[i];
#pragma unroll
    for (int off = 32; off > 0; off >>= 1)
        acc += __shfl_down(acc, off, 64);
    if ((threadIdx.x & 63) == 0) sdata[threadIdx.x >> 6] = acc;
    __syncthreads();
    if (threadIdx.x == 0) {
        const float tot = sdata[0] + sdata[1] + sdata[2] + sdata[3];
        loss_out[0] = 1.0f / (tot + 1e-6f);
    }
}

extern "C" void kernel_launch(void* const* d_in, const int* in_sizes, int n_in,
                              void* d_out, int out_size, void* d_ws, size_t ws_size,
                              hipStream_t stream) {
    const float4* pts  = (const float4*)d_in[0];
    const float* x     = (const float*)d_in[1];
    const float* y     = (const float*)d_in[2];
    const float* z     = (const float*)d_in[3];
    const float* roll  = (const float*)d_in[4];
    const float* pitch = (const float*)d_in[5];
    const float* yaw   = (const float*)d_in[6];

    float* out   = (float*)d_out;   // [0..12M) verts, [12M] loss
    float* parts = (float*)d_ws;    // NBLOCKS floats

    proj_kernel<<<NBLOCKS, NTHREADS, 0, stream>>>(pts, x, y, z, roll, pitch, yaw,
                                                  (float4*)out, parts);
    loss_kernel<<<1, 256, 0, stream>>>(parts, NBLOCKS, out + (size_t)3 * N_PTS);
}